// Round 4
// baseline (535.900 us; speedup 1.0000x reference)
//
#include <hip/hip_runtime.h>
#include <math.h>

#define G 4
// 256 threads = 4 waves; wave w owns weight rows 6w..6w+5 (24 rows).
// LDS: 2*16KB xs + 384B hraw + 16B ss + 256B M ~= 33.4KB -> 4 blocks/CU.
// 16 waves/CU from 4 INDEPENDENT blocks -> phase-decorrelated convoys.

__device__ __forceinline__ float sigmoidf_(float s) {
    return 1.0f / (1.0f + __expf(-s));
}

// Pair-fold reduction step: lanes with (l&m)==0 get X(l)+X(l^m),
// lanes with (l&m)!=0 get Y(l)+Y(l^m).
__device__ __forceinline__ float fold_(float X, float Y, int m, int l) {
    const bool hi = (l & m) != 0;
    const float a = hi ? Y : X;
    const float b = hi ? X : Y;
    return a + __shfl_xor(b, m);
}

// async global->LDS DMA: global addr per-lane, LDS base wave-uniform;
// HW writes lane i at base + i*16.
__device__ __forceinline__ void gll16(const float4* g, const float* lds) {
    __builtin_amdgcn_global_load_lds(
        (const __attribute__((address_space(1))) void*)g,
        (__attribute__((address_space(3))) void*)lds, 16, 0, 0);
}

__global__ __launch_bounds__(256)
__attribute__((amdgpu_waves_per_eu(4, 4)))   // 128-reg budget; R2 proved this shape fits (92)
void fused_route_mix(const float* __restrict__ x,
                     const float* __restrict__ scale,
                     const float* __restrict__ w_pre,
                     const float* __restrict__ w_post,
                     const float* __restrict__ w_res,
                     const float* __restrict__ ap_p,
                     const float* __restrict__ apo_p,
                     const float* __restrict__ ar_p,
                     const float* __restrict__ b_pre,
                     const float* __restrict__ b_post,
                     const float* __restrict__ b_res,
                     float* __restrict__ out,
                     int rounds)
{
    __shared__ __align__(16) float xs[2][G * 1024];  // double-buffered raw x
    __shared__ __align__(16) float hraw[G * 24];     // 24 raw dots per token
    __shared__ float sslds[G];                       // sum of squares per token
    __shared__ __align__(16) float Mlds[G * 16];     // 4x4 mixing matrix per token

    const int t = threadIdx.x;
    const int w = t >> 6;   // wave 0..3
    const int l = t & 63;   // lane 0..63

    // ---- once per block: 6 weight rows per wave, scale folded in ----
    // lane l owns elements {4l + 256mp + j : mp=0..3, j=0..3} -> float4 LDS reads.
    float wreg[6][16];
    #pragma unroll
    for (int rr = 0; rr < 6; ++rr) {
        const int k = 6 * w + rr;
        const float* wp = (k < 4) ? (w_pre + (size_t)k * 1024)
                        : (k < 8) ? (w_post + (size_t)(k - 4) * 1024)
                                  : (w_res + (size_t)(k - 8) * 1024);
        #pragma unroll
        for (int mp = 0; mp < 4; ++mp)
            #pragma unroll
            for (int j = 0; j < 4; ++j)
                wreg[rr][4 * mp + j] =
                    wp[4 * l + 256 * mp + j] * scale[4 * l + 256 * mp + j];
    }

    // uniform scalars -> SGPRs
    const float a_pre = ap_p[0], a_post = apo_p[0], a_res = ar_p[0];

    const int rstep = gridDim.x;
    int cur = 0;

    // ---- prologue: async-prefetch first round into buffer 0 ----
    {
        const float4* __restrict__ xg =
            (const float4*)(x + (size_t)blockIdx.x * (G * 1024));
        #pragma unroll
        for (int i = 0; i < G; ++i)
            gll16(xg + i * 256 + (w << 6) + l, &xs[0][i * 1024 + (w << 8)]);
    }

    for (int r = blockIdx.x; r < rounds; r += rstep) {
        const size_t base = (size_t)r * (G * 1024);

        // B1: full drain — prefetch into xs[cur] landed; other buffer free.
        __syncthreads();

        // issue next round's DMA; stays in flight across the whole round
        const int rn = r + rstep;
        if (rn < rounds) {
            const float4* __restrict__ xg =
                (const float4*)(x + (size_t)rn * (G * 1024));
            #pragma unroll
            for (int i = 0; i < G; ++i)
                gll16(xg + i * 256 + (w << 6) + l, &xs[cur ^ 1][i * 1024 + (w << 8)]);
        }

        const float* __restrict__ xb = xs[cur];

        // ---- phase 2: 6 dots + ss per wave per token ----
        #pragma unroll 2
        for (int i = 0; i < G; ++i) {
            float p0 = 0.f, p1 = 0.f, p2 = 0.f, p3 = 0.f, p4 = 0.f, p5 = 0.f;
            float ss = 0.f;
            const float4* __restrict__ xi4 = (const float4*)(xb + i * 1024);
            #pragma unroll
            for (int mp = 0; mp < 4; ++mp) {
                const float4 xv = xi4[l + 64 * mp];   // ds_read_b128, conflict-free
                const float xe[4] = {xv.x, xv.y, xv.z, xv.w};
                #pragma unroll
                for (int j = 0; j < 4; ++j) {
                    const float xj = xe[j];
                    p0 = fmaf(xj, wreg[0][4 * mp + j], p0);
                    p1 = fmaf(xj, wreg[1][4 * mp + j], p1);
                    p2 = fmaf(xj, wreg[2][4 * mp + j], p2);
                    p3 = fmaf(xj, wreg[3][4 * mp + j], p3);
                    p4 = fmaf(xj, wreg[4][4 * mp + j], p4);
                    p5 = fmaf(xj, wreg[5][4 * mp + j], p5);
                    ss = fmaf(xj, xj, ss);            // only wave 0 stores it
                }
            }
            // pack-fold butterfly: 10 shfl for 7 values
            const float q0 = fold_(p0, p1, 32, l);
            const float q1 = fold_(p2, p3, 32, l);
            const float q2 = fold_(p4, p5, 32, l);
            const float q3 = ss + __shfl_xor(ss, 32);
            const float r0v = fold_(q0, q1, 16, l);
            const float r1v = fold_(q2, q3, 16, l);
            float s = fold_(r0v, r1v, 8, l);
            s += __shfl_xor(s, 4);
            s += __shfl_xor(s, 2);
            s += __shfl_xor(s, 1);
            // vid: 0=p0(l0) 1=p1(l32) 2=p2(l16) 3=p3(l48) 4=p4(l8) 5=p5(l40) 6=ss(l24)
            if ((l & 7) == 0) {
                const int vid = ((l >> 3) & 1) * 4 + ((l >> 4) & 1) * 2 + ((l >> 5) & 1);
                if (vid < 6) hraw[i * 24 + 6 * w + vid] = s;
                else if (w == 0 && vid == 6) sslds[i] = s;
            }
        }

        // B2: LDS-only barrier — keeps prefetch (vmcnt) in flight.
        asm volatile("s_waitcnt lgkmcnt(0)\n\ts_barrier" ::: "memory");

        // ---- phase 3: sinkhorn on wave 0 only (lane -> token l&3) ----
        if (w == 0) {
            const int tk = l & (G - 1);
            const float inv = rsqrtf(sslds[tk] * (1.0f / 1024.0f) + 1e-5f);
            float hr[24];
            const float4* __restrict__ hp = (const float4*)(hraw + tk * 24);
            #pragma unroll
            for (int q = 0; q < 6; ++q) {
                const float4 hv = hp[q];
                hr[4 * q + 0] = hv.x; hr[4 * q + 1] = hv.y;
                hr[4 * q + 2] = hv.z; hr[4 * q + 3] = hv.w;
            }

            float hpre[4], hpost[4];
            #pragma unroll
            for (int j = 0; j < 4; ++j)
                hpre[j] = sigmoidf_(fmaf(a_pre * inv, hr[j], b_pre[j]));
            #pragma unroll
            for (int i = 0; i < 4; ++i)
                hpost[i] = 2.0f * sigmoidf_(fmaf(a_post * inv, hr[4 + i], b_post[i]));

            float K[4][4];
            float mx = -1e30f;
            #pragma unroll
            for (int i = 0; i < 4; ++i)
                #pragma unroll
                for (int j = 0; j < 4; ++j) {
                    const float vv = fmaf(a_res * inv, hr[8 + 4 * i + j], b_res[4 * i + j]);
                    K[i][j] = vv;
                    mx = fmaxf(mx, vv);
                }
            #pragma unroll
            for (int i = 0; i < 4; ++i)
                #pragma unroll
                for (int j = 0; j < 4; ++j)
                    K[i][j] = __expf(K[i][j] - mx);

            // sinkhorn as scaling vectors: matrix is u_i * K_ij * v_j throughout.
            float u[4] = {1.f, 1.f, 1.f, 1.f};
            float v[4] = {1.f, 1.f, 1.f, 1.f};
            for (int it = 0; it < 20; ++it) {
                #pragma unroll
                for (int j = 0; j < 4; ++j) {
                    const float S = (fmaf(u[0], K[0][j], u[1] * K[1][j]))
                                  + (fmaf(u[2], K[2][j], u[3] * K[3][j]));
                    v[j] = v[j] * __builtin_amdgcn_rcpf(fmaf(v[j], S, 1e-8f));
                }
                #pragma unroll
                for (int i = 0; i < 4; ++i) {
                    const float T = (fmaf(K[i][0], v[0], K[i][1] * v[1]))
                                  + (fmaf(K[i][2], v[2], K[i][3] * v[3]));
                    u[i] = u[i] * __builtin_amdgcn_rcpf(fmaf(u[i], T, 1e-8f));
                }
            }

            if (l < G) {   // lane l computed token l exactly
                float4* Md = (float4*)(Mlds + (l << 4));
                #pragma unroll
                for (int i2 = 0; i2 < 4; ++i2) {
                    float4 row;
                    row.x = fmaf(u[i2] * K[i2][0], v[0], hpost[i2] * hpre[0]);
                    row.y = fmaf(u[i2] * K[i2][1], v[1], hpost[i2] * hpre[1]);
                    row.z = fmaf(u[i2] * K[i2][2], v[2], hpost[i2] * hpre[2]);
                    row.w = fmaf(u[i2] * K[i2][3], v[3], hpost[i2] * hpre[3]);
                    Md[i2] = row;
                }
            }
        }

        // B3: LDS-only barrier — Mlds visible, vmcnt still in flight.
        asm volatile("s_waitcnt lgkmcnt(0)\n\ts_barrier" ::: "memory");

        // ---- phase 4: wave w produces output stream w for all G tokens ----
        #pragma unroll
        for (int i = 0; i < G; ++i) {
            const float4 m4 = ((const float4*)Mlds)[(i << 2) + w];  // broadcast
            const float4* __restrict__ xt = (const float4*)(xb + i * 1024);
            const float4 a0 = xt[0 * 64 + l];
            const float4 a1 = xt[1 * 64 + l];
            const float4 a2 = xt[2 * 64 + l];
            const float4 a3 = xt[3 * 64 + l];
            float4 o;
            o.x = m4.x * a0.x + m4.y * a1.x + m4.z * a2.x + m4.w * a3.x;
            o.y = m4.x * a0.y + m4.y * a1.y + m4.z * a2.y + m4.w * a3.y;
            o.z = m4.x * a0.z + m4.y * a1.z + m4.z * a2.z + m4.w * a3.z;
            o.w = m4.x * a0.w + m4.y * a1.w + m4.z * a2.w + m4.w * a3.w;
            ((float4*)(out + base))[(i << 8) + (w << 6) + l] = o;
        }

        cur ^= 1;
    }
}

extern "C" void kernel_launch(void* const* d_in, const int* in_sizes, int n_in,
                              void* d_out, int out_size, void* d_ws, size_t ws_size,
                              hipStream_t stream) {
    const float* x      = (const float*)d_in[0];
    const float* scale  = (const float*)d_in[1];
    const float* w_pre  = (const float*)d_in[2];
    const float* w_post = (const float*)d_in[3];
    const float* w_res  = (const float*)d_in[4];
    const float* a_pre  = (const float*)d_in[5];
    const float* a_post = (const float*)d_in[6];
    const float* a_res  = (const float*)d_in[7];
    const float* b_pre  = (const float*)d_in[8];
    const float* b_post = (const float*)d_in[9];
    const float* b_res  = (const float*)d_in[10];
    float* out = (float*)d_out;

    const int tokens = in_sizes[0] / 1024;   // B*T (n*C = 1024)
    const int rounds = tokens / G;           // 8192
    // 1024 blocks x 256 thr -> 4 independent blocks/CU on 256 CUs, 8 rounds each.
    const int grid = rounds < 1024 ? rounds : 1024;

    fused_route_mix<<<grid, 256, 0, stream>>>(
        x, scale, w_pre, w_post, w_res,
        a_pre, a_post, a_res, b_pre, b_post, b_res,
        out, rounds);
}

// Round 5
// 290.140 us; speedup vs baseline: 1.8470x; 1.8470x over previous
//
#include <hip/hip_runtime.h>
#include <math.h>

#define G 16
// 512 threads = 8 waves; wave w owns weight rows 3w..3w+2 (24 rows).
// Phase 2 reads x straight from GLOBAL (L2-resident) while staging it to a
// SINGLE 64KB LDS buffer for phase 4 (wave w stages tokens 2w,2w+1 from the
// registers it already loaded). No double buffer, no DMA, and NO vmcnt wait
// at any barrier: stores and loads never block a barrier.
// LDS: 64KB xs + 1.5KB hraw + 64B ss + 1KB M ~= 66.6KB -> 2 blocks/CU.
// waves_per_eu(4,4): 16 waves/CU = 4/SIMD; regs ~100 < 128 cap (wreg only 48).

__device__ __forceinline__ float sigmoidf_(float s) {
    return 1.0f / (1.0f + __expf(-s));
}

// Pair-fold reduction step: lanes with (l&m)==0 get X(l)+X(l^m),
// lanes with (l&m)!=0 get Y(l)+Y(l^m).
__device__ __forceinline__ float fold_(float X, float Y, int m, int l) {
    const bool hi = (l & m) != 0;
    const float a = hi ? Y : X;
    const float b = hi ? X : Y;
    return a + __shfl_xor(b, m);
}

__global__ __launch_bounds__(512)
__attribute__((amdgpu_waves_per_eu(4, 4)))
void fused_route_mix(const float* __restrict__ x,
                     const float* __restrict__ scale,
                     const float* __restrict__ w_pre,
                     const float* __restrict__ w_post,
                     const float* __restrict__ w_res,
                     const float* __restrict__ ap_p,
                     const float* __restrict__ apo_p,
                     const float* __restrict__ ar_p,
                     const float* __restrict__ b_pre,
                     const float* __restrict__ b_post,
                     const float* __restrict__ b_res,
                     float* __restrict__ out,
                     int rounds)
{
    __shared__ __align__(16) float xs[G * 1024];   // raw x, staged during phase 2
    __shared__ __align__(16) float hraw[G * 24];   // 24 raw dots per token
    __shared__ float sslds[G];                     // sum of squares per token
    __shared__ __align__(16) float Mlds[G * 16];   // 4x4 mixing matrix per token

    const int t = threadIdx.x;
    const int w = t >> 6;   // wave 0..7
    const int l = t & 63;   // lane 0..63

    // ---- once per block: 3 weight rows per wave, scale folded in ----
    // lane l owns elements {4l + 256mp + j : mp=0..3, j=0..3}.
    float wreg[3][16];
    #pragma unroll
    for (int rr = 0; rr < 3; ++rr) {
        const int k = 3 * w + rr;
        const float* wp = (k < 4) ? (w_pre + (size_t)k * 1024)
                        : (k < 8) ? (w_post + (size_t)(k - 4) * 1024)
                                  : (w_res + (size_t)(k - 8) * 1024);
        #pragma unroll
        for (int mp = 0; mp < 4; ++mp)
            #pragma unroll
            for (int j = 0; j < 4; ++j)
                wreg[rr][4 * mp + j] =
                    wp[4 * l + 256 * mp + j] * scale[4 * l + 256 * mp + j];
    }

    const float a_pre = ap_p[0], a_post = apo_p[0], a_res = ar_p[0];
    float4* const xs4 = (float4*)xs;

    for (int r = blockIdx.x; r < rounds; r += gridDim.x) {
        const size_t base = (size_t)r * (G * 1024);
        const float4* __restrict__ xg = (const float4*)(x + base);

        // B1: all waves finished last round's phase-4 LDS reads -> xs reusable.
        // lgkm-only; stores/loads (vmcnt) are never drained at a barrier.
        asm volatile("s_waitcnt lgkmcnt(0)\n\ts_barrier" ::: "memory");

        // ---- phase 2: dots from GLOBAL; stage own tokens to LDS ----
        #pragma unroll 2
        for (int i = 0; i < G; ++i) {
            float p0 = 0.f, p1 = 0.f, p2 = 0.f, ss = 0.f;
            const bool stage = ((i >> 1) == w);   // wave w stages tokens 2w,2w+1
            #pragma unroll
            for (int mp = 0; mp < 4; ++mp) {
                const float4 xv = xg[(i << 8) + (mp << 6) + l];  // coalesced, L2-hit
                if (stage)
                    xs4[(i << 8) + (mp << 6) + l] = xv;          // ds_write_b128
                const float xe[4] = {xv.x, xv.y, xv.z, xv.w};
                #pragma unroll
                for (int j = 0; j < 4; ++j) {
                    const float xj = xe[j];
                    p0 = fmaf(xj, wreg[0][4 * mp + j], p0);
                    p1 = fmaf(xj, wreg[1][4 * mp + j], p1);
                    p2 = fmaf(xj, wreg[2][4 * mp + j], p2);
                    ss = fmaf(xj, xj, ss);        // only wave 0 stores it
                }
            }
            // pack-fold butterfly: 7 shfl for 4 values
            const float q0 = fold_(p0, p1, 32, l);
            const float q1 = fold_(p2, ss, 32, l);
            float s = fold_(q0, q1, 16, l);
            s += __shfl_xor(s, 8);
            s += __shfl_xor(s, 4);
            s += __shfl_xor(s, 2);
            s += __shfl_xor(s, 1);
            // lane 0 -> p0, lane 32 -> p1, lane 16 -> p2, lane 48 -> ss
            if ((l & 15) == 0) {
                const int vid = ((l >> 5) & 1) | (((l >> 4) & 1) << 1);
                if (vid < 3) hraw[i * 24 + 3 * w + vid] = s;
                else if (w == 0) sslds[i] = s;
            }
        }

        // B2: hraw + xs staging writes visible. lgkm-only.
        asm volatile("s_waitcnt lgkmcnt(0)\n\ts_barrier" ::: "memory");

        // ---- phase 3: sinkhorn on wave 0 only (lane -> token l&15) ----
        if (w == 0) {
            const int tk = l & (G - 1);
            const float inv = rsqrtf(sslds[tk] * (1.0f / 1024.0f) + 1e-5f);
            float hr[24];
            const float4* __restrict__ hp = (const float4*)(hraw + tk * 24);
            #pragma unroll
            for (int q = 0; q < 6; ++q) {
                const float4 hv = hp[q];
                hr[4 * q + 0] = hv.x; hr[4 * q + 1] = hv.y;
                hr[4 * q + 2] = hv.z; hr[4 * q + 3] = hv.w;
            }

            float hpre[4], hpost[4];
            #pragma unroll
            for (int j = 0; j < 4; ++j)
                hpre[j] = sigmoidf_(fmaf(a_pre * inv, hr[j], b_pre[j]));
            #pragma unroll
            for (int i = 0; i < 4; ++i)
                hpost[i] = 2.0f * sigmoidf_(fmaf(a_post * inv, hr[4 + i], b_post[i]));

            float K[4][4];
            float mx = -1e30f;
            #pragma unroll
            for (int i = 0; i < 4; ++i)
                #pragma unroll
                for (int j = 0; j < 4; ++j) {
                    const float vv = fmaf(a_res * inv, hr[8 + 4 * i + j], b_res[4 * i + j]);
                    K[i][j] = vv;
                    mx = fmaxf(mx, vv);
                }
            #pragma unroll
            for (int i = 0; i < 4; ++i)
                #pragma unroll
                for (int j = 0; j < 4; ++j)
                    K[i][j] = __expf(K[i][j] - mx);

            // sinkhorn as scaling vectors: matrix is u_i * K_ij * v_j throughout.
            float u[4] = {1.f, 1.f, 1.f, 1.f};
            float v[4] = {1.f, 1.f, 1.f, 1.f};
            for (int it = 0; it < 20; ++it) {
                #pragma unroll
                for (int j = 0; j < 4; ++j) {
                    const float S = (fmaf(u[0], K[0][j], u[1] * K[1][j]))
                                  + (fmaf(u[2], K[2][j], u[3] * K[3][j]));
                    v[j] = v[j] * __builtin_amdgcn_rcpf(fmaf(v[j], S, 1e-8f));
                }
                #pragma unroll
                for (int i = 0; i < 4; ++i) {
                    const float T = (fmaf(K[i][0], v[0], K[i][1] * v[1]))
                                  + (fmaf(K[i][2], v[2], K[i][3] * v[3]));
                    u[i] = u[i] * __builtin_amdgcn_rcpf(fmaf(u[i], T, 1e-8f));
                }
            }

            if (l < G) {   // lane l computed token l exactly
                float4* Md = (float4*)(Mlds + (l << 4));
                #pragma unroll
                for (int i2 = 0; i2 < 4; ++i2) {
                    float4 row;
                    row.x = fmaf(u[i2] * K[i2][0], v[0], hpost[i2] * hpre[0]);
                    row.y = fmaf(u[i2] * K[i2][1], v[1], hpost[i2] * hpre[1]);
                    row.z = fmaf(u[i2] * K[i2][2], v[2], hpost[i2] * hpre[2]);
                    row.w = fmaf(u[i2] * K[i2][3], v[3], hpost[i2] * hpre[3]);
                    Md[i2] = row;
                }
            }
        }

        // B3: Mlds visible. lgkm-only.
        asm volatile("s_waitcnt lgkmcnt(0)\n\ts_barrier" ::: "memory");

        // ---- phase 4: wave w -> stream (w&3), tokens {2*ii + (w>>2)} ----
        const int s4 = w & 3;
        const int ihalf = w >> 2;
        #pragma unroll 2
        for (int ii = 0; ii < 8; ++ii) {
            const int i = (ii << 1) + ihalf;
            const float4 m4 = ((const float4*)Mlds)[(i << 2) + s4];  // broadcast
            const float4* __restrict__ xt = xs4 + (i << 8);
            const float4 a0 = xt[0 * 64 + l];
            const float4 a1 = xt[1 * 64 + l];
            const float4 a2 = xt[2 * 64 + l];
            const float4 a3 = xt[3 * 64 + l];
            float4 o;
            o.x = m4.x * a0.x + m4.y * a1.x + m4.z * a2.x + m4.w * a3.x;
            o.y = m4.x * a0.y + m4.y * a1.y + m4.z * a2.y + m4.w * a3.y;
            o.z = m4.x * a0.z + m4.y * a1.z + m4.z * a2.z + m4.w * a3.z;
            o.w = m4.x * a0.w + m4.y * a1.w + m4.z * a2.w + m4.w * a3.w;
            ((float4*)(out + base))[(i << 8) + (s4 << 6) + l] = o;
        }
    }
}

extern "C" void kernel_launch(void* const* d_in, const int* in_sizes, int n_in,
                              void* d_out, int out_size, void* d_ws, size_t ws_size,
                              hipStream_t stream) {
    const float* x      = (const float*)d_in[0];
    const float* scale  = (const float*)d_in[1];
    const float* w_pre  = (const float*)d_in[2];
    const float* w_post = (const float*)d_in[3];
    const float* w_res  = (const float*)d_in[4];
    const float* a_pre  = (const float*)d_in[5];
    const float* a_post = (const float*)d_in[6];
    const float* a_res  = (const float*)d_in[7];
    const float* b_pre  = (const float*)d_in[8];
    const float* b_post = (const float*)d_in[9];
    const float* b_res  = (const float*)d_in[10];
    float* out = (float*)d_out;

    const int tokens = in_sizes[0] / 1024;   // B*T (n*C = 1024)
    const int rounds = tokens / G;           // 2048
    // 512 blocks x 512 threads -> 2 blocks/CU on 256 CUs, 4 rounds each.
    const int grid = rounds < 512 ? rounds : 512;

    fused_route_mix<<<grid, 512, 0, stream>>>(
        x, scale, w_pre, w_post, w_res,
        a_pre, a_post, a_res, b_pre, b_post, b_res,
        out, rounds);
}